// Round 13
// baseline (123.773 us; speedup 1.0000x reference)
//
#include <hip/hip_runtime.h>
#include <math.h>

#define DIM 64
#define HEADS 4
#define BB 8
#define QQ 128
#define VV 128
#define NN (BB*QQ)   // 1024

typedef float f2 __attribute__((ext_vector_type(2)));
typedef float f4 __attribute__((ext_vector_type(4)));

// ---- DPP helpers (VALU, no DS); CTRL is a compile-time template constant ----
template <int CTRL>
__device__ __forceinline__ float dppf(float x) {
    return __int_as_float(__builtin_amdgcn_update_dpp(
        0, __float_as_int(x), CTRL, 0xF, 0xF, true));
}
template <int CTRL>
__device__ __forceinline__ f4 dpp4(f4 x) {
    f4 r;
    r.x = dppf<CTRL>(x.x); r.y = dppf<CTRL>(x.y);
    r.z = dppf<CTRL>(x.z); r.w = dppf<CTRL>(x.w);
    return r;
}
#define SWAP1 0xB1   // quad_perm(1,0,3,2): xor-1 partner
#define WSHR1 0x138  // wave_shr:1 : lane j <- j-1
#define WSHL1 0x130  // wave_shl:1 : lane j <- j+1

// Manual global load, 8B, immediate byte offset. Volatile: fixed program order.
#define GLOAD(dst, ptr, OFFSTR) \
    asm volatile("global_load_dwordx2 %0, %1, off offset:" OFFSTR \
                 : "=v"(dst) : "v"(ptr))

// K1: Av[h][row][j] = f32 (re,im) of sum_i values[row,i] * U[h, 64+i, j]
__global__ __launch_bounds__(256) void k_av(const float* __restrict__ values,
                                            const float* __restrict__ U_re,
                                            const float* __restrict__ U_im,
                                            f2* __restrict__ Av) {
    int tid = blockIdx.x * blockDim.x + threadIdx.x;
    int w = tid >> 6;            // 0..2047
    int j = tid & 63;
    int h = w >> 9;              // 0..3
    int r0 = (w & 511) << 1;     // first of 2 rows within head h
    const float* vrow = values + r0 * DIM;                     // wave-uniform
    const float* ur = U_re + (h * 2 * DIM + DIM) * DIM + j;    // bottom half
    const float* ui = U_im + (h * 2 * DIM + DIM) * DIM + j;
    f2 a0 = 0.f, a1 = 0.f;
    #pragma unroll 8
    for (int i = 0; i < DIM; ++i) {
        f2 u; u.x = ur[i * DIM]; u.y = ui[i * DIM];
        a0 += vrow[i] * u;                 // s_load scalars broadcast
        a1 += vrow[DIM + i] * u;
    }
    f2* out = Av + (h * 1024 + r0) * DIM + j;
    out[0] = a0; out[DIM] = a1;
}

// K2: 256 blocks = 1 block/CU; 4 waves = 4 heads; ONE wave per SIMD.
// Each wave scans FOUR rows (q0, q0+32, q0+64, q0+96; same b) as f4 state —
// 4 independent chains give intra-wave ILP; one Av load feeds all 4 rows.
// Tests the contention hypothesis: exclusive SIMD -> pure issue-rate scan.
__global__ __launch_bounds__(256, 1) void k_rnn_dense(
        const float* __restrict__ queries,
        const float* __restrict__ U_re,
        const float* __restrict__ U_im,
        const float* __restrict__ bias,
        const float* __restrict__ theta1,
        const float* __restrict__ phi1,
        const float* __restrict__ theta2,
        const float* __restrict__ phi2,
        const float* __restrict__ omega,
        const f2* __restrict__ Av,
        const float* __restrict__ W_dense,
        const float* __restrict__ b_dense,
        float* __restrict__ y) {
    int b = blockIdx.x >> 5;   // 0..7
    int q0 = blockIdx.x & 31;  // 0..31
    int t = threadIdx.x;
    int h = t >> 6;            // head = wave
    int j = t & 63;            // state dim = lane

    // ---- layer 1: t = E1 .* (C1*h + S1*swap1(h)) ----
    int k1 = j >> 1;
    float th1 = theta1[h * 32 + k1], ph1 = phi1[h * 32 + k1];
    float C1 = cosf(th1), s1v = sinf(th1);
    float S1, E1r, E1i;
    if ((j & 1) == 0) { S1 = -s1v; E1r = cosf(ph1); E1i = sinf(ph1); }
    else              { S1 =  s1v; E1r = 1.f;       E1i = 0.f;       }

    // ---- layer 2: s = PH .* (C2*t + SL*shl1(t) + SR*shr1(t)) ----
    float C2, SL, SR, p2r, p2i;
    if (j == 0 || j == 63) {
        C2 = 1.f; SL = 0.f; SR = 0.f; p2r = 1.f; p2i = 0.f;
    } else {
        int k2 = (j - 1) >> 1;
        float th2 = theta2[h * 31 + k2], ph2 = phi2[h * 31 + k2];
        float c2 = cosf(th2), s2 = sinf(th2);
        if (j & 1) { C2 = c2; SL = -s2; SR = 0.f; p2r = cosf(ph2); p2i = sinf(ph2); }
        else       { C2 = c2; SR =  s2; SL = 0.f; p2r = 1.f;       p2i = 0.f;       }
    }
    float om = omega[h * 64 + j];
    float eor = cosf(om), eoi = sinf(om);
    float PHr = p2r * eor - p2i * eoi;
    float PHi = p2r * eoi + p2i * eor;
    float bj = bias[h * 64 + j];

    // ---- Aq for the 4 rows (block-uniform bases -> s_load) ----
    int nbase = b * 128 + q0;
    const float* qrow0 = queries + (nbase      ) * DIM;
    const float* qrow1 = queries + (nbase + 32 ) * DIM;
    const float* qrow2 = queries + (nbase + 64 ) * DIM;
    const float* qrow3 = queries + (nbase + 96 ) * DIM;
    const float* ur = U_re + (h * 2 * DIM) * DIM + j;
    const float* ui = U_im + (h * 2 * DIM) * DIM + j;
    f4 Uqr = 0.f, Uqi = 0.f;   // component r = row q0+32r
    #pragma unroll 8
    for (int i = 0; i < DIM; ++i) {
        f4 a; a.x = qrow0[i]; a.y = qrow1[i]; a.z = qrow2[i]; a.w = qrow3[i];
        float wr = ur[i * DIM], wi = ui[i * DIM];
        Uqr += a * wr;
        Uqi += a * wi;
    }

    f4 Hr = 0.f, Hi = 0.f;
    auto step = [&](f2 av) {
        f4 uvr = Uqr + av.x;               // broadcast add, off-chain
        f4 uvi = Uqi + av.y;
        // layer 1
        f4 Pr = dpp4<SWAP1>(Hr), Pi = dpp4<SWAP1>(Hi);
        f4 tpr = C1 * Hr + S1 * Pr;
        f4 tpi = C1 * Hi + S1 * Pi;
        f4 Tr = E1r * tpr - E1i * tpi;
        f4 Ti = E1r * tpi + E1i * tpr;
        // layer 2
        f4 Lr = dpp4<WSHL1>(Tr), Li = dpp4<WSHL1>(Ti);
        f4 Rr = dpp4<WSHR1>(Tr), Ri = dpp4<WSHR1>(Ti);
        f4 spr = C2 * Tr + SL * Lr + SR * Rr;
        f4 spi = C2 * Ti + SL * Li + SR * Ri;
        f4 Zr = (PHr * spr - PHi * spi) + uvr;
        f4 Zi = (PHr * spi + PHi * spr) + uvi;
        // modrelu: sc = max(1 + b*rsq(|z|^2+eps), 0)   (1/m == rsq(q2))
        f4 q2;
        q2.x = fmaf(Zr.x, Zr.x, fmaf(Zi.x, Zi.x, 1e-10f));
        q2.y = fmaf(Zr.y, Zr.y, fmaf(Zi.y, Zi.y, 1e-10f));
        q2.z = fmaf(Zr.z, Zr.z, fmaf(Zi.z, Zi.z, 1e-10f));
        q2.w = fmaf(Zr.w, Zr.w, fmaf(Zi.w, Zi.w, 1e-10f));
        f4 sc;
        sc.x = fmaxf(fmaf(bj, __builtin_amdgcn_rsqf(q2.x), 1.f), 0.f);
        sc.y = fmaxf(fmaf(bj, __builtin_amdgcn_rsqf(q2.y), 1.f), 0.f);
        sc.z = fmaxf(fmaf(bj, __builtin_amdgcn_rsqf(q2.z), 1.f), 0.f);
        sc.w = fmaxf(fmaf(bj, __builtin_amdgcn_rsqf(q2.w), 1.f), 0.f);
        Hr = Zr * sc; Hi = Zi * sc;
    };

    const f2* pcur = Av + (h * 1024 + b * 128) * DIM + j;

    // prologue: batch 0 (8 steps)
    f2 c0, c1, c2v, c3, c4, c5, c6, c7;
    GLOAD(c0, pcur, "0");    GLOAD(c1, pcur, "512");
    GLOAD(c2v, pcur, "1024"); GLOAD(c3, pcur, "1536");
    GLOAD(c4, pcur, "2048"); GLOAD(c5, pcur, "2560");
    GLOAD(c6, pcur, "3072"); GLOAD(c7, pcur, "3584");
    asm volatile("s_waitcnt vmcnt(0)"
                 : "+v"(c0), "+v"(c1), "+v"(c2v), "+v"(c3),
                   "+v"(c4), "+v"(c5), "+v"(c6), "+v"(c7));

    for (int vb = 0; vb < VV; vb += 8) {
        const f2* pn = (vb < VV - 8) ? (pcur + 8 * DIM) : pcur;
        f2 x0, x1, x2, x3, x4, x5, x6, x7;
        GLOAD(x0, pn, "0");    GLOAD(x1, pn, "512");
        GLOAD(x2, pn, "1024"); GLOAD(x3, pn, "1536");
        GLOAD(x4, pn, "2048"); GLOAD(x5, pn, "2560");
        GLOAD(x6, pn, "3072"); GLOAD(x7, pn, "3584");
        step(c0); step(c1); step(c2v); step(c3);
        step(c4); step(c5); step(c6); step(c7);
        asm volatile("s_waitcnt vmcnt(0)"
                     : "+v"(x0), "+v"(x1), "+v"(x2), "+v"(x3),
                       "+v"(x4), "+v"(x5), "+v"(x6), "+v"(x7));
        c0 = x0; c1 = x1; c2v = x2; c3 = x3;
        c4 = x4; c5 = x5; c6 = x6; c7 = x7;
        pcur = pn;
    }

    // ---- fused dense for the 4 rows ----
    __shared__ float s_acc[4][HEADS * DIM];   // 4 x 256 = 4 KB
    s_acc[0][h * 64 + j] = Hr.x;
    s_acc[1][h * 64 + j] = Hr.y;
    s_acc[2][h * 64 + j] = Hr.z;
    s_acc[3][h * 64 + j] = Hr.w;
    __syncthreads();

    {   // thread t: row r = t>>6 (wave-uniform), col jj = t&63; full 256-k dot
        int r = t >> 6, jj = t & 63;
        const float* ap = s_acc[r];
        const float* Wp = W_dense + jj;
        float acc = b_dense[jj];
        #pragma unroll 8
        for (int k = 0; k < HEADS * DIM; ++k)
            acc = fmaf(ap[k], Wp[k * DIM], acc);   // ap LDS-broadcast, Wp coalesced
        y[(nbase + 32 * r) * DIM + jj] = acc;
    }
}

extern "C" void kernel_launch(void* const* d_in, const int* in_sizes, int n_in,
                              void* d_out, int out_size, void* d_ws, size_t ws_size,
                              hipStream_t stream) {
    const float* queries = (const float*)d_in[0];
    const float* values  = (const float*)d_in[1];
    const float* U_re    = (const float*)d_in[2];
    const float* U_im    = (const float*)d_in[3];
    const float* bias    = (const float*)d_in[4];
    const float* theta1  = (const float*)d_in[5];
    const float* phi1    = (const float*)d_in[6];
    const float* theta2  = (const float*)d_in[7];
    const float* phi2    = (const float*)d_in[8];
    const float* omega   = (const float*)d_in[9];
    const float* W_dense = (const float*)d_in[10];
    const float* b_dense = (const float*)d_in[11];
    float* y = (float*)d_out;

    f2* Av = (f2*)d_ws;   // HEADS*1024*64 f2 = 2 MB

    k_av<<<512, 256, 0, stream>>>(values, U_re, U_im, Av);
    k_rnn_dense<<<256, 256, 0, stream>>>(queries, U_re, U_im, bias, theta1,
                                         phi1, theta2, phi2, omega, Av,
                                         W_dense, b_dense, y);
}

// Round 14
// 113.451 us; speedup vs baseline: 1.0910x; 1.0910x over previous
//
#include <hip/hip_runtime.h>
#include <math.h>

#define DIM 64
#define HEADS 4
#define BB 8
#define QQ 128
#define VV 128
#define NN (BB*QQ)   // 1024

typedef float f2 __attribute__((ext_vector_type(2)));

// ---- DPP helpers (VALU, no DS); CTRL is a compile-time template constant ----
template <int CTRL>
__device__ __forceinline__ float dppf(float x) {
    return __int_as_float(__builtin_amdgcn_update_dpp(
        0, __float_as_int(x), CTRL, 0xF, 0xF, true));
}
#define SWAP1 0xB1   // quad_perm(1,0,3,2): xor-1 partner
#define WSHR1 0x138  // wave_shr:1 : lane j <- j-1
#define WSHL1 0x130  // wave_shl:1 : lane j <- j+1

// K1: Av[h][row][j] = f32 (re,im) of sum_i values[row,i] * U[h, 64+i, j]
__global__ __launch_bounds__(256) void k_av(const float* __restrict__ values,
                                            const float* __restrict__ U_re,
                                            const float* __restrict__ U_im,
                                            f2* __restrict__ Av) {
    int tid = blockIdx.x * blockDim.x + threadIdx.x;
    int w = tid >> 6;            // 0..2047
    int j = tid & 63;
    int h = w >> 9;              // 0..3
    int r0 = (w & 511) << 1;     // first of 2 rows within head h
    const float* vrow = values + r0 * DIM;                     // wave-uniform
    const float* ur = U_re + (h * 2 * DIM + DIM) * DIM + j;    // bottom half
    const float* ui = U_im + (h * 2 * DIM + DIM) * DIM + j;
    f2 a0 = 0.f, a1 = 0.f;
    #pragma unroll 8
    for (int i = 0; i < DIM; ++i) {
        f2 u; u.x = ur[i * DIM]; u.y = ui[i * DIM];
        a0 += vrow[i] * u;                 // s_load scalars broadcast
        a1 += vrow[DIM + i] * u;
    }
    f2* out = Av + (h * 1024 + r0) * DIM + j;
    out[0] = a0; out[DIM] = a1;
}

// K2: 1024 blocks (block = row n) = 4 blocks/CU -> 4 waves/SIMD (fills the
// per-wave issue cadence). 4 waves = 4 heads; each wave scans ONE row with
// the lean step: real Givens + real 3-tap + one fused complex phase + rsq
// modrelu. ~40 inst/step. Batch-8 register double-buffered Av loads.
__global__ __launch_bounds__(256, 4) void k_rnn_dense(
        const float* __restrict__ queries,
        const float* __restrict__ U_re,
        const float* __restrict__ U_im,
        const float* __restrict__ bias,
        const float* __restrict__ theta1,
        const float* __restrict__ phi1,
        const float* __restrict__ theta2,
        const float* __restrict__ phi2,
        const float* __restrict__ omega,
        const f2* __restrict__ Av,
        const float* __restrict__ W_dense,
        const float* __restrict__ b_dense,
        float* __restrict__ y) {
    int n = blockIdx.x;        // 0..1023 (row)
    int t = threadIdx.x;
    int h = t >> 6;            // head = wave
    int j = t & 63;            // state dim = lane
    int b = n >> 7;

    // ---- layer 1: t = E1 .* (C1*h + S1*swap1(h)) ----
    int k1 = j >> 1;
    float th1 = theta1[h * 32 + k1], ph1 = phi1[h * 32 + k1];
    float C1 = cosf(th1), s1v = sinf(th1);
    float S1, E1r, E1i;
    if ((j & 1) == 0) { S1 = -s1v; E1r = cosf(ph1); E1i = sinf(ph1); }
    else              { S1 =  s1v; E1r = 1.f;       E1i = 0.f;       }

    // ---- layer 2: s = PH .* (C2*t + SL*shl1(t) + SR*shr1(t)) ----
    float C2, SL, SR, p2r, p2i;
    if (j == 0 || j == 63) {
        C2 = 1.f; SL = 0.f; SR = 0.f; p2r = 1.f; p2i = 0.f;
    } else {
        int k2 = (j - 1) >> 1;
        float th2 = theta2[h * 31 + k2], ph2 = phi2[h * 31 + k2];
        float c2 = cosf(th2), s2 = sinf(th2);
        if (j & 1) { C2 = c2; SL = -s2; SR = 0.f; p2r = cosf(ph2); p2i = sinf(ph2); }
        else       { C2 = c2; SR =  s2; SL = 0.f; p2r = 1.f;       p2i = 0.f;       }
    }
    float om = omega[h * 64 + j];
    float eor = cosf(om), eoi = sinf(om);
    float PHr = p2r * eor - p2i * eoi;
    float PHi = p2r * eoi + p2i * eor;
    float bj = bias[h * 64 + j];

    // ---- Aq: uq = q_row . U_top[h]; query row block-uniform -> s_load ----
    const float* qrow = queries + n * DIM;
    const float* ur = U_re + (h * 2 * DIM) * DIM + j;
    const float* ui = U_im + (h * 2 * DIM) * DIM + j;
    float uqr = 0.f, uqi = 0.f;
    #pragma unroll 8
    for (int i = 0; i < DIM; ++i) {
        float a = qrow[i];
        uqr = fmaf(a, ur[i * DIM], uqr);
        uqi = fmaf(a, ui[i * DIM], uqi);
    }

    float hr = 0.f, hi = 0.f;
    auto step = [&](f2 av) {
        float uvr = uqr + av.x;            // off-chain input term
        float uvi = uqi + av.y;
        // layer 1: real Givens + phase (even lanes)
        float pr = dppf<SWAP1>(hr), pi = dppf<SWAP1>(hi);
        float tpr = fmaf(C1, hr, S1 * pr);
        float tpi = fmaf(C1, hi, S1 * pi);
        float Tr = fmaf(E1r, tpr, -E1i * tpi);
        float Ti = fmaf(E1r, tpi,  E1i * tpr);
        // layer 2: real 3-tap + fused phase
        float Lr = dppf<WSHL1>(Tr), Li = dppf<WSHL1>(Ti);
        float Rr = dppf<WSHR1>(Tr), Ri = dppf<WSHR1>(Ti);
        float spr = fmaf(C2, Tr, fmaf(SL, Lr, SR * Rr));
        float spi = fmaf(C2, Ti, fmaf(SL, Li, SR * Ri));
        float zr = fmaf(PHr, spr, fmaf(-PHi, spi, uvr));
        float zi = fmaf(PHr, spi, fmaf( PHi, spr, uvi));
        // modrelu: sc = max(1 + b*rsq(|z|^2+eps), 0)  (1/m == rsq)
        float q2 = fmaf(zr, zr, fmaf(zi, zi, 1e-10f));
        float rs = __builtin_amdgcn_rsqf(q2);
        float sc = fmaxf(fmaf(bj, rs, 1.f), 0.f);
        hr = zr * sc; hi = zi * sc;
    };

    const f2* p = Av + (h * 1024 + b * 128) * DIM + j;

    // batch-8 register double-buffer
    f2 buf[8], nxt[8];
    #pragma unroll
    for (int k = 0; k < 8; ++k) buf[k] = p[k * DIM];

    for (int vb = 0; vb < VV; vb += 8) {
        const f2* pn = p + ((vb < VV - 8) ? 8 * DIM : 0);
        #pragma unroll
        for (int k = 0; k < 8; ++k) nxt[k] = pn[k * DIM];
        p = pn;
        #pragma unroll
        for (int k = 0; k < 8; ++k) step(buf[k]);
        #pragma unroll
        for (int k = 0; k < 8; ++k) buf[k] = nxt[k];
    }

    // ---- fused dense for row n ----
    __shared__ float s_acc[HEADS * DIM];   // 256
    __shared__ float s_part[256];
    s_acc[h * 64 + j] = hr;                // Re(hT)
    __syncthreads();

    {   // thread t: k-quarter qq = t>>6, col jj = t&63
        int qq = t >> 6, jj = t & 63;
        const float* Wp = W_dense + (qq * 64) * DIM + jj;
        const float* ap = &s_acc[qq * 64];
        float part = 0.f;
        #pragma unroll 8
        for (int k = 0; k < 64; ++k)
            part = fmaf(ap[k], Wp[k * DIM], part);   // ap broadcast, Wp coalesced
        s_part[t] = part;
    }
    __syncthreads();
    if (t < 64) {
        y[n * DIM + t] = b_dense[t] + s_part[t] + s_part[64 + t]
                       + s_part[128 + t] + s_part[192 + t];
    }
}

extern "C" void kernel_launch(void* const* d_in, const int* in_sizes, int n_in,
                              void* d_out, int out_size, void* d_ws, size_t ws_size,
                              hipStream_t stream) {
    const float* queries = (const float*)d_in[0];
    const float* values  = (const float*)d_in[1];
    const float* U_re    = (const float*)d_in[2];
    const float* U_im    = (const float*)d_in[3];
    const float* bias    = (const float*)d_in[4];
    const float* theta1  = (const float*)d_in[5];
    const float* phi1    = (const float*)d_in[6];
    const float* theta2  = (const float*)d_in[7];
    const float* phi2    = (const float*)d_in[8];
    const float* omega   = (const float*)d_in[9];
    const float* W_dense = (const float*)d_in[10];
    const float* b_dense = (const float*)d_in[11];
    float* y = (float*)d_out;

    f2* Av = (f2*)d_ws;   // HEADS*1024*64 f2 = 2 MB

    k_av<<<512, 256, 0, stream>>>(values, U_re, U_im, Av);
    k_rnn_dense<<<1024, 256, 0, stream>>>(queries, U_re, U_im, bias, theta1,
                                          phi1, theta2, phi2, omega, Av,
                                          W_dense, b_dense, y);
}